// Round 1
// 975.095 us; speedup vs baseline: 1.0826x; 1.0826x over previous
//
#include <hip/hip_runtime.h>
#include <math.h>

#define NN 1024
#define FF 128
#define LRELU_ALPHA 0.2f
#define NEGVAL -9000000000000000.0f

// ---------------------------------------------------------------------------
// Kernel 1: Wh = h @ W_w + W_b  (1024x128)
//           s_i[i] = Wh[i,:] . a_w[0:128]   + a_b   (a_b folded in)
//           s_j[i] = Wh[i,:] . a_w[128:256]
// One block per row i, 128 threads (thread o owns output feature o).
// ---------------------------------------------------------------------------
__global__ __launch_bounds__(128) void wh_kernel(
    const float* __restrict__ h, const float* __restrict__ W_w,
    const float* __restrict__ W_b, const float* __restrict__ a_w,
    const float* __restrict__ a_b,
    float* __restrict__ Wh, float* __restrict__ s_i, float* __restrict__ s_j)
{
    const int i = blockIdx.x;
    const int o = threadIdx.x;           // 0..127
    __shared__ float h_s[FF];
    __shared__ float red_i[2];
    __shared__ float red_j[2];

    h_s[o] = h[i * FF + o];
    __syncthreads();

    float acc = W_b[o];
#pragma unroll 8
    for (int k = 0; k < FF; ++k)
        acc = fmaf(h_s[k], W_w[k * FF + o], acc);

    Wh[(size_t)i * FF + o] = acc;

    float pi = acc * a_w[o];         // a_i
    float pj = acc * a_w[FF + o];    // a_j
#pragma unroll
    for (int off = 32; off; off >>= 1) {
        pi += __shfl_xor(pi, off, 64);
        pj += __shfl_xor(pj, off, 64);
    }
    const int wave = o >> 6;
    if ((o & 63) == 0) { red_i[wave] = pi; red_j[wave] = pj; }
    __syncthreads();
    if (o == 0) s_i[i] = red_i[0] + red_i[1] + a_b[0];
    if (o == 1) s_j[i] = red_j[0] + red_j[1];
}

// ---------------------------------------------------------------------------
// Kernel 2: one block (1024 threads = 16 waves) per row i.
// Pass 1 (adj-gated): wave w owns the j-stripe [64w, 64w+64). Ballot the adj
//   stripe into a uniform 64-bit mask; init the stripe to NEGVAL; then pop TWO
//   active j's per iteration (half-wave per j, float4/lane, 5-step half-wave
//   shuffle reduce — same summation order as before for active entries).
//   Masked j's cost nothing: adj~Bernoulli(0.5) halves e_h/de HBM traffic.
// Softmax over the LDS row (all-masked rows degenerate to uniform, = jax).
// Pass 2: out[i,f] = elu( sum_j attn[j] * Wh[j,f] ), Wh from L2.
// ---------------------------------------------------------------------------
__global__ __launch_bounds__(1024) void attn_kernel(
    const float* __restrict__ e_h, const float* __restrict__ de,
    const int* __restrict__ adj, const float* __restrict__ a_w,
    const float* __restrict__ Wh, const float* __restrict__ s_i,
    const float* __restrict__ s_j, float* __restrict__ out)
{
    const int i    = blockIdx.x;
    const int tid  = threadIdx.x;
    const int lane = tid & 63;
    const int wave = tid >> 6;           // 0..15
    const int half = lane >> 5;          // 0 or 1 (which j of the pair)
    const int hl   = lane & 31;          // lane within half

    __shared__ float e_row[NN];          // scores, then attention weights
    __shared__ float red2[NN];           // pass-2 partial sums
    __shared__ float wred[16];

    // per-lane fragments of a_e, a_d: half-wave covers one j, 4 floats/lane
    const float4 ae4 = *(const float4*)(a_w + 2 * FF + hl * 4);
    const float4 ad4 = *(const float4*)(a_w + 3 * FF + hl * 4);
    const float  si  = s_i[i];
    const size_t rowbase = (size_t)i * NN * FF;

    // ---- pass 1: adj-compacted scores ----
    const int jbase = wave * 64;         // this wave's j-stripe
    unsigned long long mask =
        __ballot(adj[(size_t)i * NN + jbase + lane] > 0);

    // init own stripe to NEG; same-wave LDS program order makes this safe
    e_row[jbase + lane] = NEGVAL;

    while (mask) {
        const int b0 = (int)__builtin_ctzll(mask); mask &= mask - 1;
        int b1 = b0;                      // odd count: both halves do b0
        if (mask) { b1 = (int)__builtin_ctzll(mask); mask &= mask - 1; }
        const int j = jbase + (half ? b1 : b0);
        const size_t off = rowbase + (size_t)j * FF + hl * 4;  // 512B/half-wave
        const float4 eh4 = *(const float4*)(e_h + off);
        const float4 de4 = *(const float4*)(de + off);
        float p = eh4.x * ae4.x + eh4.y * ae4.y + eh4.z * ae4.z + eh4.w * ae4.w
                + de4.x * ad4.x + de4.y * ad4.y + de4.z * ad4.z + de4.w * ad4.w;
#pragma unroll
        for (int o = 16; o; o >>= 1) p += __shfl_xor(p, o, 64);  // within half
        if (hl == 0) {
            float v = si + s_j[j] + p;
            e_row[j] = (v >= 0.f) ? v : LRELU_ALPHA * v;   // active: no mask
        }
    }
    __syncthreads();

    // ---- softmax over e_row (each thread owns one element) ----
    const float v = e_row[tid];
    float m = v;
#pragma unroll
    for (int o = 32; o; o >>= 1) m = fmaxf(m, __shfl_xor(m, o, 64));
    if (lane == 0) wred[wave] = m;
    __syncthreads();
    m = wred[0];
#pragma unroll
    for (int w = 1; w < 16; ++w) m = fmaxf(m, wred[w]);

    const float p = __expf(v - m);
    float s = p;
#pragma unroll
    for (int o = 32; o; o >>= 1) s += __shfl_xor(s, o, 64);
    __syncthreads();                      // all wred reads done before reuse
    if (lane == 0) wred[wave] = s;
    __syncthreads();
    s = wred[0];
#pragma unroll
    for (int w = 1; w < 16; ++w) s += wred[w];

    e_row[tid] = p * (1.0f / s);          // normalized attention weight
    __syncthreads();

    // ---- pass 2: h' = attn @ Wh, then ELU ----
    const int f = tid & 127;              // feature
    const int g = tid >> 7;               // 0..7 j-groups
    float acc = 0.f;
    for (int j = g; j < NN; j += 8)
        acc = fmaf(e_row[j], Wh[(size_t)j * FF + f], acc);
    red2[tid] = acc;
    __syncthreads();
    if (g == 0) {
        float r = acc;
#pragma unroll
        for (int gg = 1; gg < 8; ++gg) r += red2[gg * 128 + f];
        out[(size_t)i * FF + f] = (r > 0.f) ? r : (__expf(r) - 1.0f);
    }
}

extern "C" void kernel_launch(void* const* d_in, const int* in_sizes, int n_in,
                              void* d_out, int out_size, void* d_ws, size_t ws_size,
                              hipStream_t stream) {
    const float* h   = (const float*)d_in[0];
    const float* e_h = (const float*)d_in[1];
    const float* de  = (const float*)d_in[2];
    const int*   adj = (const int*)d_in[3];
    const float* W_w = (const float*)d_in[4];
    const float* W_b = (const float*)d_in[5];
    const float* a_w = (const float*)d_in[6];
    const float* a_b = (const float*)d_in[7];
    float* out = (float*)d_out;

    // workspace layout: Wh (1024*128 f32) | s_i (1024) | s_j (1024)
    float* Wh  = (float*)d_ws;
    float* s_i = Wh + (size_t)NN * FF;
    float* s_j = s_i + NN;

    wh_kernel<<<NN, 128, 0, stream>>>(h, W_w, W_b, a_w, a_b, Wh, s_i, s_j);
    attn_kernel<<<NN, 1024, 0, stream>>>(e_h, de, adj, a_w, Wh, s_i, s_j, out);
}